// Round 10
// baseline (105.244 us; speedup 1.0000x reference)
//
#include <hip/hip_runtime.h>

typedef __attribute__((ext_vector_type(8))) short short8;
typedef __attribute__((ext_vector_type(4))) float f32x4;
typedef __attribute__((ext_vector_type(4))) int i32x4;

#define C0F 0.28209479177387814f
#define C1F 0.4886025119029199f
#define IS3 0.5773502691896258f
#define IS2 0.7071067811865476f
#define ASC 0.040555354f   // 1/sqrt(2*19*16)
#define AVC 0.033113308f   // 1/sqrt(3*19*16)

#define WB 51200                 // weight bytes: 5 mats * 20 taps * 512 B (tap 19 = zeros), [m][tap][w16][u16]

// hexagonal stencil offsets (tap 19 = pad -> (0,0), weights are zero)
#define OX0 0
#define SEL(t_, arr0, arr1) ((taph) ? (arr1) : (arr0))

__constant__ int dummy_unused[1] = {0};

__device__ inline unsigned short f32_bf16(float x) {
    unsigned int u = __float_as_uint(x);
    return (unsigned short)((u + 0x7FFF + ((u >> 16) & 1)) >> 16);
}

#define GLD16(gp, lp) __builtin_amdgcn_global_load_lds( \
    (const __attribute__((address_space(1))) unsigned int*)(gp), \
    (__attribute__((address_space(3))) unsigned int*)(lp), 16, 0, 0)

// ---- prepass: blocks [0,2048): feat -> de-interleaved LINEAR bf16 [px][s16|v0|v1|v2] (32 px/block)
//               blocks [2048,2148): weights -> bf16 [m][tap20][w16][u16], tap19 = 0
__global__ __launch_bounds__(256) void prep_kernel(
    const float* __restrict__ feat,
    const float* __restrict__ w000, const float* __restrict__ w011,
    const float* __restrict__ w101, const float* __restrict__ w110,
    const float* __restrict__ w111, unsigned char* __restrict__ ws)
{
    const int t = threadIdx.x;
    if (blockIdx.x >= 2048) {
        int o = (blockIdx.x - 2048) * 256 + t;          // [0, 25600)
        int m = o / 5120;
        int r1 = o - m * 5120;
        int tap = r1 >> 8;                               // 0..19
        int r2 = r1 & 255;
        int w = r2 >> 4;
        int u = r2 & 15;
        const float* W = (m == 0) ? w000 : (m == 1) ? w011 : (m == 2) ? w101 : (m == 3) ? w110 : w111;
        float val = (tap < 19) ? W[tap * 256 + u * 16 + w] : 0.0f;
        ((unsigned short*)ws)[o] = f32_bf16(val);        // linear o == [m][tap][w][u16]
        return;
    }
    __shared__ float raw[2048];                          // 32 px * 64 ch
    const int P0 = blockIdx.x * 32;
    const float4* src = (const float4*)feat + (size_t)P0 * 16;
    float4 l0 = src[t * 2];
    float4 l1 = src[t * 2 + 1];
    *(float4*)&raw[t * 8] = l0;
    *(float4*)&raw[t * 8 + 4] = l1;
    __syncthreads();
    const int p = t >> 3;                                // local pixel
    const int c = t & 7;                                 // 16B chunk id
    const float* r = &raw[p * 64];
    int ch0, stride;
    if (c < 2) { ch0 = c * 8; stride = 1; }
    else { int i = (c - 2) >> 1, uh = (c - 2) & 1; ch0 = 16 + i + 24 * uh; stride = 3; }
    unsigned int pk[4];
#pragma unroll
    for (int e = 0; e < 4; ++e) {
        unsigned int lo = f32_bf16(r[ch0 + stride * (2 * e)]);
        unsigned int hi = f32_bf16(r[ch0 + stride * (2 * e + 1)]);
        pk[e] = lo | (hi << 16);
    }
    const int PX = P0 + p;
    *(i32x4*)(ws + WB + (size_t)PX * 128 + (c << 4)) = *(const i32x4*)pk;   // LINEAR, no swizzle
}

// ---- main: weights in LDS (GLD16), A-fragments direct from global (L1/L2), no feat staging
__global__ __launch_bounds__(256) void spinconv_mfma(
    const unsigned char* __restrict__ fbf, const unsigned char* __restrict__ wbf,
    const float* __restrict__ spin, float* __restrict__ out)
{
    __shared__ char smem[WB];
    const int tid = threadIdx.x, b = blockIdx.x;
    const int n = b >> 7;
    const int X0 = ((b >> 3) & 15) << 3;   // 16 x-tiles of 8
    const int Y0 = (b & 7) << 4;           // 8 y-tiles of 16
    const int lane = tid & 63, wv = tid >> 6;
    const int lx = lane & 15;
    const int q = lane >> 4;
    const int u0b = (q & 1) << 4;          // byte offset of u-half
    const int taph = q >> 1;               // which tap of the K=32 pair

    // stage weights: 50 full 1024B chunks (51200 B), wave-uniform predicates
    for (int j = 0; j < 13; ++j) {
        const int cid = j * 4 + wv;
        if (cid < 50)
            GLD16(wbf + cid * 1024 + lane * 16, smem + cid * 1024);
    }
    __syncthreads();

    const int xa = X0 + 2 * wv;            // M-tile x-row A (wave-uniform)
    const int y  = Y0 + lx;                // pixel y (per-lane)
    const size_t nb = (size_t)n << 14;

    f32x4 aS0{0,0,0,0}, aS1{0,0,0,0}, aB0{0,0,0,0}, aB1{0,0,0,0}, aB2{0,0,0,0},
          aC0{0,0,0,0}, aC1{0,0,0,0}, aC2{0,0,0,0}, aD0{0,0,0,0}, aD1{0,0,0,0}, aD2{0,0,0,0};
    f32x4 bS0{0,0,0,0}, bS1{0,0,0,0}, bB0{0,0,0,0}, bB1{0,0,0,0}, bB2{0,0,0,0},
          bC0{0,0,0,0}, bC1{0,0,0,0}, bC2{0,0,0,0}, bD0{0,0,0,0}, bD1{0,0,0,0}, bD2{0,0,0,0};

    // hexagonal tap offsets, compile-time pairs selected by taph
    constexpr int OXc[20] = {0, 1,1,0,-1,-1,0, 2,2,2,1,0,-1,-2,-2,-2,-1,0,1, 0};
    constexpr int OYc[20] = {0, 1,0,-1,-1,0,1, 2,1,0,-1,-2,-2,-2,-1,0,1,2,2, 0};

#pragma unroll
    for (int t = 0; t < 10; ++t) {
        const int tap = 2 * t + taph;
        const int ox = taph ? OXc[2 * t + 1] : OXc[2 * t];
        const int oy = taph ? OYc[2 * t + 1] : OYc[2 * t];
        const int gy  = (y + oy) & 127;
        const int gxa = (xa + ox) & 127;
        const int gxb = (xa + 1 + ox) & 127;
        const unsigned char* pa = fbf + (((nb + (gxa << 7) + gy)) << 7) + u0b;
        const unsigned char* pb = fbf + (((nb + (gxb << 7) + gy)) << 7) + u0b;
        short8 xs  = *(const short8*)(pa);
        short8 x0  = *(const short8*)(pa + 32);
        short8 x1  = *(const short8*)(pa + 64);
        short8 x2  = *(const short8*)(pa + 96);
        short8 ys  = *(const short8*)(pb);
        short8 y0  = *(const short8*)(pb + 32);
        short8 y1  = *(const short8*)(pb + 64);
        short8 y2  = *(const short8*)(pb + 96);
        const char* bb = smem + tap * 512 + lx * 32 + u0b;   // [tap][w][u16] addressing (round-8 verified)
        short8 b000 = *(const short8*)(bb);
        short8 b011 = *(const short8*)(bb + 10240);
        short8 b101 = *(const short8*)(bb + 20480);
        short8 b110 = *(const short8*)(bb + 30720);
        short8 b111 = *(const short8*)(bb + 40960);
        aS0 = __builtin_amdgcn_mfma_f32_16x16x32_bf16(xs, b000, aS0, 0, 0, 0);
        aS1 = __builtin_amdgcn_mfma_f32_16x16x32_bf16(xs, b011, aS1, 0, 0, 0);
        aB0 = __builtin_amdgcn_mfma_f32_16x16x32_bf16(x0, b101, aB0, 0, 0, 0);
        aC0 = __builtin_amdgcn_mfma_f32_16x16x32_bf16(x0, b110, aC0, 0, 0, 0);
        aD0 = __builtin_amdgcn_mfma_f32_16x16x32_bf16(x0, b111, aD0, 0, 0, 0);
        aB1 = __builtin_amdgcn_mfma_f32_16x16x32_bf16(x1, b101, aB1, 0, 0, 0);
        aC1 = __builtin_amdgcn_mfma_f32_16x16x32_bf16(x1, b110, aC1, 0, 0, 0);
        aD1 = __builtin_amdgcn_mfma_f32_16x16x32_bf16(x1, b111, aD1, 0, 0, 0);
        aB2 = __builtin_amdgcn_mfma_f32_16x16x32_bf16(x2, b101, aB2, 0, 0, 0);
        aC2 = __builtin_amdgcn_mfma_f32_16x16x32_bf16(x2, b110, aC2, 0, 0, 0);
        aD2 = __builtin_amdgcn_mfma_f32_16x16x32_bf16(x2, b111, aD2, 0, 0, 0);
        bS0 = __builtin_amdgcn_mfma_f32_16x16x32_bf16(ys, b000, bS0, 0, 0, 0);
        bS1 = __builtin_amdgcn_mfma_f32_16x16x32_bf16(ys, b011, bS1, 0, 0, 0);
        bB0 = __builtin_amdgcn_mfma_f32_16x16x32_bf16(y0, b101, bB0, 0, 0, 0);
        bC0 = __builtin_amdgcn_mfma_f32_16x16x32_bf16(y0, b110, bC0, 0, 0, 0);
        bD0 = __builtin_amdgcn_mfma_f32_16x16x32_bf16(y0, b111, bD0, 0, 0, 0);
        bB1 = __builtin_amdgcn_mfma_f32_16x16x32_bf16(y1, b101, bB1, 0, 0, 0);
        bC1 = __builtin_amdgcn_mfma_f32_16x16x32_bf16(y1, b110, bC1, 0, 0, 0);
        bD1 = __builtin_amdgcn_mfma_f32_16x16x32_bf16(y1, b111, bD1, 0, 0, 0);
        bB2 = __builtin_amdgcn_mfma_f32_16x16x32_bf16(y2, b101, bB2, 0, 0, 0);
        bC2 = __builtin_amdgcn_mfma_f32_16x16x32_bf16(y2, b110, bC2, 0, 0, 0);
        bD2 = __builtin_amdgcn_mfma_f32_16x16x32_bf16(y2, b111, bD2, 0, 0, 0);
    }

    // spin fetch (post-loop, frees VGPRs during K-loop)
    float sp[24];
#pragma unroll
    for (int ti = 0; ti < 2; ++ti)
#pragma unroll
        for (int r = 0; r < 4; ++r) {
            const int x = X0 + 2 * wv + ti;
            const int yy = Y0 + (q << 2) + r;
            const int P = (((n << 7) + x) << 7) + yy;
            sp[ti * 12 + r * 3 + 0] = spin[3 * P + 0];
            sp[ti * 12 + r * 3 + 1] = spin[3 * P + 1];
            sp[ti * 12 + r * 3 + 2] = spin[3 * P + 2];
        }

    // epilogue: D row = q*4+r = y-offset, col = lx = w  (round-8 verified)
    const int w = lx;
#pragma unroll
    for (int r = 0; r < 4; ++r) {
        const int yy = Y0 + (q << 2) + r;
        {
            const int x = X0 + 2 * wv;
            const int P = (((n << 7) + x) << 7) + yy;
            const float s0 = C1F * sp[r * 3 + 1];
            const float s1 = C1F * sp[r * 3 + 2];
            const float s2 = C1F * sp[r * 3 + 0];
            float* o = out + (size_t)P * 64;
            o[w] = ASC * (C0F * aS0[r] + IS3 * (s0 * aC0[r] + s1 * aC1[r] + s2 * aC2[r]));
            o[16 + 3 * w + 0] = AVC * (s0 * aS1[r] + C0F * aB0[r] + IS2 * (s2 * aD1[r] - s1 * aD2[r]));
            o[16 + 3 * w + 1] = AVC * (s1 * aS1[r] + C0F * aB1[r] + IS2 * (s0 * aD2[r] - s2 * aD0[r]));
            o[16 + 3 * w + 2] = AVC * (s2 * aS1[r] + C0F * aB2[r] + IS2 * (s1 * aD0[r] - s0 * aD1[r]));
        }
        {
            const int x = X0 + 2 * wv + 1;
            const int P = (((n << 7) + x) << 7) + yy;
            const float s0 = C1F * sp[12 + r * 3 + 1];
            const float s1 = C1F * sp[12 + r * 3 + 2];
            const float s2 = C1F * sp[12 + r * 3 + 0];
            float* o = out + (size_t)P * 64;
            o[w] = ASC * (C0F * bS0[r] + IS3 * (s0 * bC0[r] + s1 * bC1[r] + s2 * bC2[r]));
            o[16 + 3 * w + 0] = AVC * (s0 * bS1[r] + C0F * bB0[r] + IS2 * (s2 * bD1[r] - s1 * bD2[r]));
            o[16 + 3 * w + 1] = AVC * (s1 * bS1[r] + C0F * bB1[r] + IS2 * (s0 * bD2[r] - s2 * bD0[r]));
            o[16 + 3 * w + 2] = AVC * (s2 * bS1[r] + C0F * bB2[r] + IS2 * (s1 * bD0[r] - s0 * bD1[r]));
        }
    }
}

extern "C" void kernel_launch(void* const* d_in, const int* in_sizes, int n_in,
                              void* d_out, int out_size, void* d_ws, size_t ws_size,
                              hipStream_t stream) {
    const float* feat = (const float*)d_in[0];
    const float* spin = (const float*)d_in[1];
    const float* w000 = (const float*)d_in[2];
    const float* w011 = (const float*)d_in[3];
    const float* w101 = (const float*)d_in[4];
    const float* w110 = (const float*)d_in[5];
    const float* w111 = (const float*)d_in[6];
    float* out = (float*)d_out;
    unsigned char* ws = (unsigned char*)d_ws;   // [0,51200): bf16 weights; [51200,+8.39MB): bf16 feat

    hipLaunchKernelGGL(prep_kernel, dim3(2148), dim3(256), 0, stream,
                       feat, w000, w011, w101, w110, w111, ws);
    hipLaunchKernelGGL(spinconv_mfma, dim3(512), dim3(256), 0, stream,
                       ws + WB, ws, spin, out);
}